// Round 1
// baseline (147.465 us; speedup 1.0000x reference)
//
#include <hip/hip_runtime.h>
#include <hip/hip_bf16.h>

typedef __bf16 bf16_t;
typedef __attribute__((ext_vector_type(8))) __bf16 bf16x8;
typedef __attribute__((ext_vector_type(4))) float f32x4;

#define B_ 8
#define T_ 2048
#define C_ 1024
#define H_ 64

// ---------------------------------------------------------------------------
// Kernel 1: convert + transpose weights -> Wt[w][h][k] bf16  (w: 0=q,1=k,2=v)
// ---------------------------------------------------------------------------
__global__ __launch_bounds__(256) void wprep_kernel(
    const float* __restrict__ Wq, const float* __restrict__ Wk,
    const float* __restrict__ Wv, bf16_t* __restrict__ Wt) {
  int idx = blockIdx.x * 256 + threadIdx.x;
  if (idx >= 3 * H_ * C_) return;
  int w   = idx >> 16;       // 64*1024 = 65536 elements per matrix
  int rem = idx & 65535;
  int h   = rem >> 10;
  int k   = rem & 1023;
  const float* W = (w == 0) ? Wq : ((w == 1) ? Wk : Wv);
  Wt[idx] = (bf16_t)W[k * H_ + h];
}

// ---------------------------------------------------------------------------
// Kernel 2: QKV projection. Block = 4 waves = 64 rows x 192 cols.
// Wave: 32 rows x 96 cols -> 2x6 fragments of mfma_f32_16x16x32_bf16.
// A-frags: x fp32 loaded as 2x float4, converted in-register to bf16.
// B-frags: 16B contiguous loads from Wt (L2-resident).
// q is written scaled by H^-0.5 = 0.125 (exact in bf16).
// v is written TRANSPOSED: vt[b][h][t]  (for the PV MFMA B-operand later).
// ---------------------------------------------------------------------------
__global__ __launch_bounds__(256) void qkv_kernel(
    const float* __restrict__ x, const bf16_t* __restrict__ Wt,
    bf16_t* __restrict__ qb, bf16_t* __restrict__ kb, bf16_t* __restrict__ vt) {
  const int wave = threadIdx.x >> 6;
  const int lane = threadIdx.x & 63;
  const int l15  = lane & 15;
  const int lq   = lane >> 4;
  const int row0  = blockIdx.x * 64 + (wave >> 1) * 32;  // 2 m-frags (32 rows)
  const int ncol0 = (wave & 1) * 96;                     // 6 n-frags (96 cols)

  f32x4 acc[2][6];
#pragma unroll
  for (int i = 0; i < 2; ++i)
#pragma unroll
    for (int j = 0; j < 6; ++j) acc[i][j] = (f32x4){0.f, 0.f, 0.f, 0.f};

  for (int k0 = 0; k0 < C_; k0 += 32) {
    bf16x8 af[2];
#pragma unroll
    for (int i = 0; i < 2; ++i) {
      const float* xp = x + (size_t)(row0 + i * 16 + l15) * C_ + k0 + lq * 8;
      float4 u0 = *(const float4*)xp;
      float4 u1 = *(const float4*)(xp + 4);
      bf16x8 a;
      a[0] = (bf16_t)u0.x; a[1] = (bf16_t)u0.y; a[2] = (bf16_t)u0.z; a[3] = (bf16_t)u0.w;
      a[4] = (bf16_t)u1.x; a[5] = (bf16_t)u1.y; a[6] = (bf16_t)u1.z; a[7] = (bf16_t)u1.w;
      af[i] = a;
    }
    bf16x8 bfr[6];
#pragma unroll
    for (int j = 0; j < 6; ++j) {
      int col  = ncol0 + j * 16 + l15;
      int wsel = col >> 6;
      int h    = col & 63;
      bfr[j] = *(const bf16x8*)(Wt + (size_t)(wsel * 64 + h) * C_ + k0 + lq * 8);
    }
#pragma unroll
    for (int i = 0; i < 2; ++i)
#pragma unroll
      for (int j = 0; j < 6; ++j)
        acc[i][j] = __builtin_amdgcn_mfma_f32_16x16x32_bf16(af[i], bfr[j], acc[i][j], 0, 0, 0);
  }

  // Epilogue: D layout col=lane&15, row=(lane>>4)*4+reg
#pragma unroll
  for (int i = 0; i < 2; ++i) {
#pragma unroll
    for (int j = 0; j < 6; ++j) {
      int col  = ncol0 + j * 16 + l15;
      int wsel = col >> 6;
      int h    = col & 63;
#pragma unroll
      for (int r = 0; r < 4; ++r) {
        int m   = row0 + i * 16 + lq * 4 + r;
        float v = acc[i][j][r];
        if (wsel == 0) {
          qb[(size_t)m * H_ + h] = (bf16_t)(v * 0.125f);
        } else if (wsel == 1) {
          kb[(size_t)m * H_ + h] = (bf16_t)v;
        } else {
          int bb = m >> 11, t = m & 2047;
          vt[((size_t)bb * H_ + h) * T_ + t] = (bf16_t)v;
        }
      }
    }
  }
}

// ---------------------------------------------------------------------------
// Kernel 3: causal flash attention. Block = (batch, 64-row q-tile), 4 waves.
// Wave owns 16 q-rows. Q in registers; K/V frags direct from global (L2).
// Online softmax in fp32; P -> bf16 via per-wave private LDS strip.
// ---------------------------------------------------------------------------
__global__ __launch_bounds__(256) void attn_kernel(
    const bf16_t* __restrict__ qb, const bf16_t* __restrict__ kb,
    const bf16_t* __restrict__ vt, float* __restrict__ out) {
  __shared__ bf16_t plds[4][16][72];  // per-wave 16x64 P strip, padded
  const int wave = threadIdx.x >> 6;
  const int lane = threadIdx.x & 63;
  const int l15  = lane & 15;
  const int lq   = lane >> 4;
  const int b    = blockIdx.x >> 5;
  const int qi   = blockIdx.x & 31;
  const bf16_t* qB = qb + (size_t)b * T_ * H_;
  const bf16_t* kB = kb + (size_t)b * T_ * H_;
  const bf16_t* vB = vt + (size_t)b * H_ * T_;
  const int rowbase = qi * 64 + wave * 16;

  bf16x8 qf[2];
#pragma unroll
  for (int k0 = 0; k0 < 2; ++k0)
    qf[k0] = *(const bf16x8*)(qB + (size_t)(rowbase + l15) * H_ + k0 * 32 + lq * 8);

  float m_run[4], l_run[4];
  f32x4 oacc[4];
#pragma unroll
  for (int r = 0; r < 4; ++r) { m_run[r] = -1e30f; l_run[r] = 0.f; }
#pragma unroll
  for (int nh = 0; nh < 4; ++nh) oacc[nh] = (f32x4){0.f, 0.f, 0.f, 0.f};

  for (int kt = 0; kt <= qi; ++kt) {
    f32x4 sacc[4];
#pragma unroll
    for (int n = 0; n < 4; ++n) sacc[n] = (f32x4){0.f, 0.f, 0.f, 0.f};

#pragma unroll
    for (int n = 0; n < 4; ++n) {
#pragma unroll
      for (int k0 = 0; k0 < 2; ++k0) {
        bf16x8 kf = *(const bf16x8*)(kB + (size_t)(kt * 64 + n * 16 + l15) * H_ + k0 * 32 + lq * 8);
        sacc[n] = __builtin_amdgcn_mfma_f32_16x16x32_bf16(qf[k0], kf, sacc[n], 0, 0, 0);
      }
    }

    if (kt == qi) {  // causal mask within diagonal tile
#pragma unroll
      for (int n = 0; n < 4; ++n)
#pragma unroll
        for (int r = 0; r < 4; ++r)
          if (n * 16 + l15 > wave * 16 + lq * 4 + r) sacc[n][r] = -1e30f;
    }

    // online softmax per q-row (rows live in 16-lane groups)
#pragma unroll
    for (int r = 0; r < 4; ++r) {
      float mx = fmaxf(fmaxf(sacc[0][r], sacc[1][r]), fmaxf(sacc[2][r], sacc[3][r]));
      mx = fmaxf(mx, __shfl_xor(mx, 1));
      mx = fmaxf(mx, __shfl_xor(mx, 2));
      mx = fmaxf(mx, __shfl_xor(mx, 4));
      mx = fmaxf(mx, __shfl_xor(mx, 8));
      float mnew = fmaxf(m_run[r], mx);
      float corr = __expf(m_run[r] - mnew);
      float psum = 0.f;
#pragma unroll
      for (int n = 0; n < 4; ++n) {
        float p = __expf(sacc[n][r] - mnew);
        psum += p;
        plds[wave][lq * 4 + r][n * 16 + l15] = (bf16_t)p;
      }
      psum += __shfl_xor(psum, 1);
      psum += __shfl_xor(psum, 2);
      psum += __shfl_xor(psum, 4);
      psum += __shfl_xor(psum, 8);
      l_run[r] = l_run[r] * corr + psum;
      m_run[r] = mnew;
#pragma unroll
      for (int nh = 0; nh < 4; ++nh) oacc[nh][r] *= corr;
    }
    __syncthreads();  // P strip visible (within-wave; cheap insurance)

    bf16x8 pa[2];
    pa[0] = *(const bf16x8*)&plds[wave][l15][lq * 8];
    pa[1] = *(const bf16x8*)&plds[wave][l15][32 + lq * 8];

#pragma unroll
    for (int nh = 0; nh < 4; ++nh) {
#pragma unroll
      for (int k0 = 0; k0 < 2; ++k0) {
        bf16x8 vf = *(const bf16x8*)(vB + (size_t)(nh * 16 + l15) * T_ + kt * 64 + k0 * 32 + lq * 8);
        oacc[nh] = __builtin_amdgcn_mfma_f32_16x16x32_bf16(pa[k0], vf, oacc[nh], 0, 0, 0);
      }
    }
    __syncthreads();
  }

  // epilogue: normalize and write fp32 (B,T,H)
#pragma unroll
  for (int r = 0; r < 4; ++r) {
    float inv = 1.0f / l_run[r];
    int t = rowbase + lq * 4 + r;
#pragma unroll
    for (int nh = 0; nh < 4; ++nh)
      out[((size_t)b * T_ + t) * H_ + nh * 16 + l15] = oacc[nh][r] * inv;
  }
}

// ---------------------------------------------------------------------------
extern "C" void kernel_launch(void* const* d_in, const int* in_sizes, int n_in,
                              void* d_out, int out_size, void* d_ws, size_t ws_size,
                              hipStream_t stream) {
  const float* x  = (const float*)d_in[0];
  const float* Wq = (const float*)d_in[1];
  const float* Wk = (const float*)d_in[2];
  const float* Wv = (const float*)d_in[3];

  char* ws = (char*)d_ws;
  bf16_t* Wt = (bf16_t*)(ws);                    // 384 KB
  bf16_t* qb = (bf16_t*)(ws + (1u << 20));       // 2 MB  (scaled q, bf16)
  bf16_t* kb = (bf16_t*)(ws + 3u * (1u << 20));  // 2 MB
  bf16_t* vt = (bf16_t*)(ws + 5u * (1u << 20));  // 2 MB  (v transposed [b][h][t])
  float* outp = (float*)d_out;

  hipLaunchKernelGGL(wprep_kernel, dim3(768), dim3(256), 0, stream, Wq, Wk, Wv, Wt);
  hipLaunchKernelGGL(qkv_kernel, dim3(256), dim3(256), 0, stream, x, Wt, qb, kb, vt);
  hipLaunchKernelGGL(attn_kernel, dim3(256), dim3(256), 0, stream, qb, kb, vt, outp);
}

// Round 2
// 130.835 us; speedup vs baseline: 1.1271x; 1.1271x over previous
//
#include <hip/hip_runtime.h>
#include <hip/hip_bf16.h>

typedef __bf16 bf16_t;
typedef __attribute__((ext_vector_type(4))) __bf16 bf16x4;
typedef __attribute__((ext_vector_type(8))) __bf16 bf16x8;
typedef __attribute__((ext_vector_type(4))) float f32x4;

#define B_ 8
#define T_ 2048
#define C_ 1024
#define H_ 64

// ---------------------------------------------------------------------------
// Kernel 1: convert + transpose weights -> Wt[w][h][k] bf16 (w: 0=q,1=k,2=v)
// Coalesced via LDS transpose. Grid: 3 w x 16 k-tiles = 48 blocks.
// ---------------------------------------------------------------------------
__global__ __launch_bounds__(256) void wprep_kernel(
    const float* __restrict__ Wq, const float* __restrict__ Wk,
    const float* __restrict__ Wv, bf16_t* __restrict__ Wt) {
  __shared__ float tile[64][68];
  const int t  = threadIdx.x;
  const int w  = blockIdx.x >> 4;
  const int k0 = (blockIdx.x & 15) * 64;
  const float* W = (w == 0) ? Wq : ((w == 1) ? Wk : Wv);

#pragma unroll
  for (int i = 0; i < 4; ++i) {
    int kl  = (t >> 4) + 16 * i;
    int col = (t & 15) * 4;
    float4 u = *(const float4*)(W + (size_t)(k0 + kl) * H_ + col);
    tile[kl][col + 0] = u.x; tile[kl][col + 1] = u.y;
    tile[kl][col + 2] = u.z; tile[kl][col + 3] = u.w;
  }
  __syncthreads();
#pragma unroll
  for (int i = 0; i < 4; ++i) {
    int h  = (t >> 4) + 16 * i;
    int kl = (t & 15) * 4;
    bf16x4 v;
    v[0] = (bf16_t)tile[kl + 0][h]; v[1] = (bf16_t)tile[kl + 1][h];
    v[2] = (bf16_t)tile[kl + 2][h]; v[3] = (bf16_t)tile[kl + 3][h];
    *(bf16x4*)(Wt + (size_t)w * 65536 + (size_t)h * C_ + k0 + kl) = v;
  }
}

// ---------------------------------------------------------------------------
// Kernel 2: QKV projection. Grid 512 blocks (2/CU). Block = 32 rows x 192 cols,
// 4 waves; wave = 16 rows x 96 cols = 1x6 frags of mfma_f32_16x16x32_bf16.
// q written scaled by 0.125; v written transposed vt[b][h][t].
// ---------------------------------------------------------------------------
__global__ __launch_bounds__(256) void qkv_kernel(
    const float* __restrict__ x, const bf16_t* __restrict__ Wt,
    bf16_t* __restrict__ qb, bf16_t* __restrict__ kb, bf16_t* __restrict__ vt) {
  const int wave = threadIdx.x >> 6;
  const int lane = threadIdx.x & 63;
  const int l15  = lane & 15;
  const int lq   = lane >> 4;
  const int row0  = blockIdx.x * 32 + (wave >> 1) * 16;
  const int ncol0 = (wave & 1) * 96;

  f32x4 acc[6];
#pragma unroll
  for (int j = 0; j < 6; ++j) acc[j] = (f32x4){0.f, 0.f, 0.f, 0.f};

  for (int k0 = 0; k0 < C_; k0 += 32) {
    const float* xp = x + (size_t)(row0 + l15) * C_ + k0 + lq * 8;
    float4 u0 = *(const float4*)xp;
    float4 u1 = *(const float4*)(xp + 4);
    bf16x8 af;
    af[0] = (bf16_t)u0.x; af[1] = (bf16_t)u0.y; af[2] = (bf16_t)u0.z; af[3] = (bf16_t)u0.w;
    af[4] = (bf16_t)u1.x; af[5] = (bf16_t)u1.y; af[6] = (bf16_t)u1.z; af[7] = (bf16_t)u1.w;

    bf16x8 bfr[6];
#pragma unroll
    for (int j = 0; j < 6; ++j) {
      int col  = ncol0 + j * 16 + l15;
      int wsel = col >> 6;
      int h    = col & 63;
      bfr[j] = *(const bf16x8*)(Wt + (size_t)(wsel * 64 + h) * C_ + k0 + lq * 8);
    }
#pragma unroll
    for (int j = 0; j < 6; ++j)
      acc[j] = __builtin_amdgcn_mfma_f32_16x16x32_bf16(af, bfr[j], acc[j], 0, 0, 0);
  }

#pragma unroll
  for (int j = 0; j < 6; ++j) {
    int col  = ncol0 + j * 16 + l15;
    int wsel = col >> 6;
    int h    = col & 63;
#pragma unroll
    for (int r = 0; r < 4; ++r) {
      int m   = row0 + lq * 4 + r;
      float v = acc[j][r];
      if (wsel == 0) {
        qb[(size_t)m * H_ + h] = (bf16_t)(v * 0.125f);
      } else if (wsel == 1) {
        kb[(size_t)m * H_ + h] = (bf16_t)v;
      } else {
        int bb = m >> 11, tt = m & 2047;
        vt[((size_t)bb * H_ + h) * T_ + tt] = (bf16_t)v;
      }
    }
  }
}

// ---------------------------------------------------------------------------
// Kernel 3: causal flash attention, split-KV within block.
// Grid 256 = (b, 64-row q-tile). Block = 1024 threads = 16 waves:
//   wave w: rg = w&3 (16 q-rows), ch = w>>2 (kv chunk, kt = ch, ch+4, ...).
// No in-loop barriers. End: LDS merge of 4 chunk-partials per row-group.
// ---------------------------------------------------------------------------
__global__ __launch_bounds__(1024) void attn_kernel(
    const bf16_t* __restrict__ qb, const bf16_t* __restrict__ kb,
    const bf16_t* __restrict__ vt, float* __restrict__ out) {
  // union: P-strips (16 waves x 16x72 bf16 = 36864B) before barrier,
  // combine buffers (49152 + 1536 B) after.
  __shared__ __align__(16) char smem[50688];
  bf16_t (*plds)[16][72]   = (bf16_t (*)[16][72])smem;          // [wave][row][col]
  float (*co)[4][16][64]   = (float (*)[4][16][64])smem;        // [ch-1][rg][row][col]
  float (*cml)[4][16][2]   = (float (*)[4][16][2])(smem + 49152);

  const int wave = threadIdx.x >> 6;
  const int lane = threadIdx.x & 63;
  const int l15  = lane & 15;
  const int lq   = lane >> 4;
  const int rg   = wave & 3;
  const int ch   = wave >> 2;
  const int b    = blockIdx.x >> 5;
  const int qi   = blockIdx.x & 31;
  const bf16_t* qB = qb + (size_t)b * T_ * H_;
  const bf16_t* kB = kb + (size_t)b * T_ * H_;
  const bf16_t* vB = vt + (size_t)b * H_ * T_;
  const int rowbase = qi * 64 + rg * 16;

  bf16x8 qf[2];
#pragma unroll
  for (int k0 = 0; k0 < 2; ++k0)
    qf[k0] = *(const bf16x8*)(qB + (size_t)(rowbase + l15) * H_ + k0 * 32 + lq * 8);

  float m_run[4], l_run[4];
  f32x4 oacc[4];
#pragma unroll
  for (int r = 0; r < 4; ++r) { m_run[r] = -1e30f; l_run[r] = 0.f; }
#pragma unroll
  for (int nh = 0; nh < 4; ++nh) oacc[nh] = (f32x4){0.f, 0.f, 0.f, 0.f};

  for (int kt = ch; kt <= qi; kt += 4) {
    f32x4 sacc[4];
#pragma unroll
    for (int n = 0; n < 4; ++n) sacc[n] = (f32x4){0.f, 0.f, 0.f, 0.f};

#pragma unroll
    for (int n = 0; n < 4; ++n) {
#pragma unroll
      for (int k0 = 0; k0 < 2; ++k0) {
        bf16x8 kf = *(const bf16x8*)(kB + (size_t)(kt * 64 + n * 16 + l15) * H_ + k0 * 32 + lq * 8);
        sacc[n] = __builtin_amdgcn_mfma_f32_16x16x32_bf16(qf[k0], kf, sacc[n], 0, 0, 0);
      }
    }

    if (kt == qi) {  // diagonal tile: causal mask
#pragma unroll
      for (int n = 0; n < 4; ++n)
#pragma unroll
        for (int r = 0; r < 4; ++r)
          if (n * 16 + l15 > rg * 16 + lq * 4 + r) sacc[n][r] = -1e30f;
    }

#pragma unroll
    for (int r = 0; r < 4; ++r) {
      float mx = fmaxf(fmaxf(sacc[0][r], sacc[1][r]), fmaxf(sacc[2][r], sacc[3][r]));
      mx = fmaxf(mx, __shfl_xor(mx, 1));
      mx = fmaxf(mx, __shfl_xor(mx, 2));
      mx = fmaxf(mx, __shfl_xor(mx, 4));
      mx = fmaxf(mx, __shfl_xor(mx, 8));
      float mnew = fmaxf(m_run[r], mx);
      float corr = __expf(m_run[r] - mnew);
      float psum = 0.f;
#pragma unroll
      for (int n = 0; n < 4; ++n) {
        float p = __expf(sacc[n][r] - mnew);
        psum += p;
        plds[wave][lq * 4 + r][n * 16 + l15] = (bf16_t)p;
      }
      psum += __shfl_xor(psum, 1);
      psum += __shfl_xor(psum, 2);
      psum += __shfl_xor(psum, 4);
      psum += __shfl_xor(psum, 8);
      l_run[r] = l_run[r] * corr + psum;
      m_run[r] = mnew;
#pragma unroll
      for (int nh = 0; nh < 4; ++nh) oacc[nh][r] *= corr;
    }

    // per-wave P re-layout (write->read same wave; compiler inserts lgkmcnt)
    bf16x8 pa[2];
    pa[0] = *(const bf16x8*)&plds[wave][l15][lq * 8];
    pa[1] = *(const bf16x8*)&plds[wave][l15][32 + lq * 8];

#pragma unroll
    for (int nh = 0; nh < 4; ++nh) {
#pragma unroll
      for (int k0 = 0; k0 < 2; ++k0) {
        bf16x8 vf = *(const bf16x8*)(vB + (size_t)(nh * 16 + l15) * T_ + kt * 64 + k0 * 32 + lq * 8);
        oacc[nh] = __builtin_amdgcn_mfma_f32_16x16x32_bf16(pa[k0], vf, oacc[nh], 0, 0, 0);
      }
    }
  }

  __syncthreads();  // all waves done with plds; smem becomes combine buffers

  if (ch > 0) {
#pragma unroll
    for (int r = 0; r < 4; ++r) {
      int row = lq * 4 + r;
#pragma unroll
      for (int nh = 0; nh < 4; ++nh)
        co[ch - 1][rg][row][nh * 16 + l15] = oacc[nh][r];
      if (l15 == 0) {
        cml[ch - 1][rg][row][0] = m_run[r];
        cml[ch - 1][rg][row][1] = l_run[r];
      }
    }
  }
  __syncthreads();

  if (ch == 0) {
#pragma unroll
    for (int r = 0; r < 4; ++r) {
      int row = lq * 4 + r;
      float M = m_run[r], L = l_run[r];
      float o[4];
#pragma unroll
      for (int nh = 0; nh < 4; ++nh) o[nh] = oacc[nh][r];
#pragma unroll
      for (int s = 0; s < 3; ++s) {
        float ms = cml[s][rg][row][0];
        float ls = cml[s][rg][row][1];
        float Mn = fmaxf(M, ms);
        float a  = __expf(M - Mn);
        float bs = __expf(ms - Mn);
        L = L * a + ls * bs;
#pragma unroll
        for (int nh = 0; nh < 4; ++nh)
          o[nh] = o[nh] * a + co[s][rg][row][nh * 16 + l15] * bs;
        M = Mn;
      }
      float inv = 1.0f / L;
      int tt = rowbase + row;
#pragma unroll
      for (int nh = 0; nh < 4; ++nh)
        out[((size_t)b * T_ + tt) * H_ + nh * 16 + l15] = o[nh] * inv;
    }
  }
}

// ---------------------------------------------------------------------------
extern "C" void kernel_launch(void* const* d_in, const int* in_sizes, int n_in,
                              void* d_out, int out_size, void* d_ws, size_t ws_size,
                              hipStream_t stream) {
  const float* x  = (const float*)d_in[0];
  const float* Wq = (const float*)d_in[1];
  const float* Wk = (const float*)d_in[2];
  const float* Wv = (const float*)d_in[3];

  char* ws = (char*)d_ws;
  bf16_t* Wt = (bf16_t*)(ws);                    // 384 KB
  bf16_t* qb = (bf16_t*)(ws + (1u << 20));       // 2 MB (scaled q)
  bf16_t* kb = (bf16_t*)(ws + 3u * (1u << 20));  // 2 MB
  bf16_t* vt = (bf16_t*)(ws + 5u * (1u << 20));  // 2 MB (v transposed [b][h][t])
  float* outp = (float*)d_out;

  hipLaunchKernelGGL(wprep_kernel, dim3(48), dim3(256), 0, stream, Wq, Wk, Wv, Wt);
  hipLaunchKernelGGL(qkv_kernel, dim3(512), dim3(256), 0, stream, x, Wt, qb, kb, vt);
  hipLaunchKernelGGL(attn_kernel, dim3(256), dim3(1024), 0, stream, qb, kb, vt, outp);
}

// Round 3
// 98.110 us; speedup vs baseline: 1.5031x; 1.3336x over previous
//
#include <hip/hip_runtime.h>
#include <hip/hip_bf16.h>

typedef __bf16 bf16_t;
typedef __attribute__((ext_vector_type(4))) __bf16 bf16x4;
typedef __attribute__((ext_vector_type(8))) __bf16 bf16x8;
typedef __attribute__((ext_vector_type(4))) float f32x4;

#define B_ 8
#define T_ 2048
#define C_ 1024
#define H_ 64

// ---------------------------------------------------------------------------
// Kernel 1: convert + transpose weights -> Wt[w][h][k] bf16 (w: 0=q,1=k,2=v)
// ---------------------------------------------------------------------------
__global__ __launch_bounds__(256) void wprep_kernel(
    const float* __restrict__ Wq, const float* __restrict__ Wk,
    const float* __restrict__ Wv, bf16_t* __restrict__ Wt) {
  __shared__ float tile[64][68];
  const int t  = threadIdx.x;
  const int w  = blockIdx.x >> 4;
  const int k0 = (blockIdx.x & 15) * 64;
  const float* W = (w == 0) ? Wq : ((w == 1) ? Wk : Wv);

#pragma unroll
  for (int i = 0; i < 4; ++i) {
    int kl  = (t >> 4) + 16 * i;
    int col = (t & 15) * 4;
    float4 u = *(const float4*)(W + (size_t)(k0 + kl) * H_ + col);
    tile[kl][col + 0] = u.x; tile[kl][col + 1] = u.y;
    tile[kl][col + 2] = u.z; tile[kl][col + 3] = u.w;
  }
  __syncthreads();
#pragma unroll
  for (int i = 0; i < 4; ++i) {
    int h  = (t >> 4) + 16 * i;
    int kl = (t & 15) * 4;
    bf16x4 v;
    v[0] = (bf16_t)tile[kl + 0][h]; v[1] = (bf16_t)tile[kl + 1][h];
    v[2] = (bf16_t)tile[kl + 2][h]; v[3] = (bf16_t)tile[kl + 3][h];
    *(bf16x4*)(Wt + (size_t)w * 65536 + (size_t)h * C_ + k0 + kl) = v;
  }
}

// ---------------------------------------------------------------------------
// Kernel 2: QKV projection v3. Grid 512 (2 blocks/CU). Block = 32 rows x 192
// cols, 4 waves; wave = 32 rows x 48 cols = 2x3 frags of 16x16x32 MFMA.
// x staged via double-buffered, XOR-swizzled LDS tile (shared by all waves,
// each row read once). B-frags register-prefetched one k-step ahead.
// ---------------------------------------------------------------------------
__global__ __launch_bounds__(256) void qkv_kernel(
    const float* __restrict__ x, const bf16_t* __restrict__ Wt,
    bf16_t* __restrict__ qb, bf16_t* __restrict__ kb, bf16_t* __restrict__ vt) {
  __shared__ float xs[2][32][32];  // [buf][row][k], swizzled: byte^((row&7)<<4)
  const int tid  = threadIdx.x;
  const int wave = tid >> 6;
  const int lane = tid & 63;
  const int l15  = lane & 15;
  const int lq   = lane >> 4;
  const int row0 = blockIdx.x * 32;

  // per-n-frag B info (col -> which matrix, which head col)
  int wsel_[3], h_[3];
  const bf16_t* bp[3];
#pragma unroll
  for (int j = 0; j < 3; ++j) {
    int col  = wave * 48 + j * 16 + l15;
    wsel_[j] = col >> 6;
    h_[j]    = col & 63;
    bp[j] = Wt + (size_t)(wsel_[j] * 64 + h_[j]) * C_ + lq * 8;
  }

  // staging map: thread -> (row sr, linear float col sfc); write swizzled
  const int sr  = tid >> 3;
  const int sfc = (tid & 7) * 4;
  const float* src = x + (size_t)(row0 + sr) * C_ + sfc;
  const int dstoff = sr * 32 + (sfc ^ ((sr & 7) * 4));  // float index in tile

  f32x4 acc[2][3];
#pragma unroll
  for (int m = 0; m < 2; ++m)
#pragma unroll
    for (int j = 0; j < 3; ++j) acc[m][j] = (f32x4){0.f, 0.f, 0.f, 0.f};

  // prologue: stage k-step 0 into buf0; preload B[0]
  {
    float4 v = *(const float4*)src;
    *(float4*)(&xs[0][0][0] + dstoff) = v;
  }
  bf16x8 bcur[3];
#pragma unroll
  for (int j = 0; j < 3; ++j) bcur[j] = *(const bf16x8*)bp[j];
  __syncthreads();

  for (int k = 0; k < 32; ++k) {
    const int kn = k + 1;
    float4 vstage;
    bf16x8 bnext[3];
    if (kn < 32) {
      vstage = *(const float4*)(src + kn * 32);  // issue early, lands at barrier
#pragma unroll
      for (int j = 0; j < 3; ++j) bnext[j] = *(const bf16x8*)(bp[j] + kn * 32);
    }

    // A-frags from swizzled LDS
    const char* base = (const char*)&xs[k & 1][0][0];
    bf16x8 af[2];
#pragma unroll
    for (int m = 0; m < 2; ++m) {
      int r  = m * 16 + l15;
      int sw = (r & 7) << 4;
      f32x4 a0 = *(const f32x4*)(base + r * 128 + ((lq * 32) ^ sw));
      f32x4 a1 = *(const f32x4*)(base + r * 128 + ((lq * 32 + 16) ^ sw));
      bf16x8 a;
      a[0] = (bf16_t)a0[0]; a[1] = (bf16_t)a0[1]; a[2] = (bf16_t)a0[2]; a[3] = (bf16_t)a0[3];
      a[4] = (bf16_t)a1[0]; a[5] = (bf16_t)a1[1]; a[6] = (bf16_t)a1[2]; a[7] = (bf16_t)a1[3];
      af[m] = a;
    }

#pragma unroll
    for (int m = 0; m < 2; ++m)
#pragma unroll
      for (int j = 0; j < 3; ++j)
        acc[m][j] = __builtin_amdgcn_mfma_f32_16x16x32_bf16(af[m], bcur[j], acc[m][j], 0, 0, 0);

    if (kn < 32) {
      *(float4*)(&xs[kn & 1][0][0] + dstoff) = vstage;  // write-late (T14)
#pragma unroll
      for (int j = 0; j < 3; ++j) bcur[j] = bnext[j];
    }
    __syncthreads();
  }

  // epilogue
#pragma unroll
  for (int m = 0; m < 2; ++m)
#pragma unroll
    for (int j = 0; j < 3; ++j)
#pragma unroll
      for (int r = 0; r < 4; ++r) {
        int mm  = row0 + m * 16 + lq * 4 + r;
        float v = acc[m][j][r];
        if (wsel_[j] == 0) {
          qb[(size_t)mm * H_ + h_[j]] = (bf16_t)(v * 0.125f);
        } else if (wsel_[j] == 1) {
          kb[(size_t)mm * H_ + h_[j]] = (bf16_t)v;
        } else {
          int bb = mm >> 11, tt = mm & 2047;
          vt[((size_t)bb * H_ + h_[j]) * T_ + tt] = (bf16_t)v;
        }
      }
}

// ---------------------------------------------------------------------------
// Kernel 3: causal flash attention, split-KV within block.
// Grid 256 = (b, 64-row q-tile). Block = 1024 threads = 16 waves:
//   wave w: rg = w&3 (16 q-rows), ch = w>>2 (kv chunk, kt = ch, ch+4, ...).
// K loads batched ahead of QK MFMAs; V loads issued before softmax (latency
// hides under the VALU phase); setprio around MFMA clusters (T5).
// ---------------------------------------------------------------------------
__global__ __launch_bounds__(1024) void attn_kernel(
    const bf16_t* __restrict__ qb, const bf16_t* __restrict__ kb,
    const bf16_t* __restrict__ vt, float* __restrict__ out) {
  __shared__ __align__(16) char smem[50688];
  bf16_t (*plds)[16][72]   = (bf16_t (*)[16][72])smem;          // [wave][row][col]
  float (*co)[4][16][64]   = (float (*)[4][16][64])smem;        // [ch-1][rg][row][col]
  float (*cml)[4][16][2]   = (float (*)[4][16][2])(smem + 49152);

  const int wave = threadIdx.x >> 6;
  const int lane = threadIdx.x & 63;
  const int l15  = lane & 15;
  const int lq   = lane >> 4;
  const int rg   = wave & 3;
  const int ch   = wave >> 2;
  const int b    = blockIdx.x >> 5;
  const int qi   = blockIdx.x & 31;
  const bf16_t* qB = qb + (size_t)b * T_ * H_;
  const bf16_t* kB = kb + (size_t)b * T_ * H_;
  const bf16_t* vB = vt + (size_t)b * H_ * T_;
  const int rowbase = qi * 64 + rg * 16;

  bf16x8 qf[2];
#pragma unroll
  for (int k0 = 0; k0 < 2; ++k0)
    qf[k0] = *(const bf16x8*)(qB + (size_t)(rowbase + l15) * H_ + k0 * 32 + lq * 8);

  float m_run[4], l_run[4];
  f32x4 oacc[4];
#pragma unroll
  for (int r = 0; r < 4; ++r) { m_run[r] = -1e30f; l_run[r] = 0.f; }
#pragma unroll
  for (int nh = 0; nh < 4; ++nh) oacc[nh] = (f32x4){0.f, 0.f, 0.f, 0.f};

  for (int kt = ch; kt <= qi; kt += 4) {
    // batch all K-fragment loads, then MFMA
    bf16x8 kf[4][2];
#pragma unroll
    for (int n = 0; n < 4; ++n)
#pragma unroll
      for (int k0 = 0; k0 < 2; ++k0)
        kf[n][k0] = *(const bf16x8*)(kB + (size_t)(kt * 64 + n * 16 + l15) * H_ + k0 * 32 + lq * 8);

    f32x4 sacc[4];
#pragma unroll
    for (int n = 0; n < 4; ++n) sacc[n] = (f32x4){0.f, 0.f, 0.f, 0.f};
    __builtin_amdgcn_s_setprio(1);
#pragma unroll
    for (int n = 0; n < 4; ++n)
#pragma unroll
      for (int k0 = 0; k0 < 2; ++k0)
        sacc[n] = __builtin_amdgcn_mfma_f32_16x16x32_bf16(qf[k0], kf[n][k0], sacc[n], 0, 0, 0);
    __builtin_amdgcn_s_setprio(0);

    // issue V loads now; they fly during the softmax VALU phase
    bf16x8 vf[4][2];
#pragma unroll
    for (int nh = 0; nh < 4; ++nh)
#pragma unroll
      for (int k0 = 0; k0 < 2; ++k0)
        vf[nh][k0] = *(const bf16x8*)(vB + (size_t)(nh * 16 + l15) * T_ + kt * 64 + k0 * 32 + lq * 8);

    if (kt == qi) {  // diagonal tile: causal mask
#pragma unroll
      for (int n = 0; n < 4; ++n)
#pragma unroll
        for (int r = 0; r < 4; ++r)
          if (n * 16 + l15 > rg * 16 + lq * 4 + r) sacc[n][r] = -1e30f;
    }

#pragma unroll
    for (int r = 0; r < 4; ++r) {
      float mx = fmaxf(fmaxf(sacc[0][r], sacc[1][r]), fmaxf(sacc[2][r], sacc[3][r]));
      mx = fmaxf(mx, __shfl_xor(mx, 1));
      mx = fmaxf(mx, __shfl_xor(mx, 2));
      mx = fmaxf(mx, __shfl_xor(mx, 4));
      mx = fmaxf(mx, __shfl_xor(mx, 8));
      float mnew = fmaxf(m_run[r], mx);
      float corr = __expf(m_run[r] - mnew);
      float psum = 0.f;
#pragma unroll
      for (int n = 0; n < 4; ++n) {
        float p = __expf(sacc[n][r] - mnew);
        psum += p;
        plds[wave][lq * 4 + r][n * 16 + l15] = (bf16_t)p;
      }
      psum += __shfl_xor(psum, 1);
      psum += __shfl_xor(psum, 2);
      psum += __shfl_xor(psum, 4);
      psum += __shfl_xor(psum, 8);
      l_run[r] = l_run[r] * corr + psum;
      m_run[r] = mnew;
#pragma unroll
      for (int nh = 0; nh < 4; ++nh) oacc[nh][r] *= corr;
    }

    // per-wave P re-layout (same-wave write->read; compiler inserts lgkmcnt)
    bf16x8 pa[2];
    pa[0] = *(const bf16x8*)&plds[wave][l15][lq * 8];
    pa[1] = *(const bf16x8*)&plds[wave][l15][32 + lq * 8];

    __builtin_amdgcn_s_setprio(1);
#pragma unroll
    for (int nh = 0; nh < 4; ++nh)
#pragma unroll
      for (int k0 = 0; k0 < 2; ++k0)
        oacc[nh] = __builtin_amdgcn_mfma_f32_16x16x32_bf16(pa[k0], vf[nh][k0], oacc[nh], 0, 0, 0);
    __builtin_amdgcn_s_setprio(0);
  }

  __syncthreads();  // all waves done with plds; smem becomes combine buffers

  if (ch > 0) {
#pragma unroll
    for (int r = 0; r < 4; ++r) {
      int row = lq * 4 + r;
#pragma unroll
      for (int nh = 0; nh < 4; ++nh)
        co[ch - 1][rg][row][nh * 16 + l15] = oacc[nh][r];
      if (l15 == 0) {
        cml[ch - 1][rg][row][0] = m_run[r];
        cml[ch - 1][rg][row][1] = l_run[r];
      }
    }
  }
  __syncthreads();

  if (ch == 0) {
#pragma unroll
    for (int r = 0; r < 4; ++r) {
      int row = lq * 4 + r;
      float M = m_run[r], L = l_run[r];
      float o[4];
#pragma unroll
      for (int nh = 0; nh < 4; ++nh) o[nh] = oacc[nh][r];
#pragma unroll
      for (int s = 0; s < 3; ++s) {
        float ms = cml[s][rg][row][0];
        float ls = cml[s][rg][row][1];
        float Mn = fmaxf(M, ms);
        float a  = __expf(M - Mn);
        float bs = __expf(ms - Mn);
        L = L * a + ls * bs;
#pragma unroll
        for (int nh = 0; nh < 4; ++nh)
          o[nh] = o[nh] * a + co[s][rg][row][nh * 16 + l15] * bs;
        M = Mn;
      }
      float inv = 1.0f / L;
      int tt = rowbase + row;
#pragma unroll
      for (int nh = 0; nh < 4; ++nh)
        out[((size_t)b * T_ + tt) * H_ + nh * 16 + l15] = o[nh] * inv;
    }
  }
}

// ---------------------------------------------------------------------------
extern "C" void kernel_launch(void* const* d_in, const int* in_sizes, int n_in,
                              void* d_out, int out_size, void* d_ws, size_t ws_size,
                              hipStream_t stream) {
  const float* x  = (const float*)d_in[0];
  const float* Wq = (const float*)d_in[1];
  const float* Wk = (const float*)d_in[2];
  const float* Wv = (const float*)d_in[3];

  char* ws = (char*)d_ws;
  bf16_t* Wt = (bf16_t*)(ws);                    // 384 KB
  bf16_t* qb = (bf16_t*)(ws + (1u << 20));       // 2 MB (scaled q)
  bf16_t* kb = (bf16_t*)(ws + 3u * (1u << 20));  // 2 MB
  bf16_t* vt = (bf16_t*)(ws + 5u * (1u << 20));  // 2 MB (v transposed [b][h][t])
  float* outp = (float*)d_out;

  hipLaunchKernelGGL(wprep_kernel, dim3(48), dim3(256), 0, stream, Wq, Wk, Wv, Wt);
  hipLaunchKernelGGL(qkv_kernel, dim3(512), dim3(256), 0, stream, x, Wt, qb, kb, vt);
  hipLaunchKernelGGL(attn_kernel, dim3(256), dim3(1024), 0, stream, qb, kb, vt, outp);
}